// Round 6
// baseline (1564.673 us; speedup 1.0000x reference)
//
#include <hip/hip_runtime.h>
#include <math.h>

#define DD 768
#define FF 3072
#define SS 512
#define BB 16
#define NH 12
#define DH 64
#define NL 4
#define MM (BB*SS)   // 8192

typedef __attribute__((ext_vector_type(8))) short short8;
typedef __attribute__((ext_vector_type(4))) float f32x4;

__device__ __forceinline__ unsigned short f2bf(float f) {
  unsigned u = __float_as_uint(f);
  return (unsigned short)((u + 0x7FFFu + ((u >> 16) & 1u)) >> 16);
}
__device__ __forceinline__ float bf2f(unsigned short s) {
  return __uint_as_float(((unsigned)s) << 16);
}

#define GLOAD_LDS(g, l) \
  __builtin_amdgcn_global_load_lds((const __attribute__((address_space(1))) void*)(g), \
                                   (__attribute__((address_space(3))) void*)(l), 16, 0, 0)

// ---------------- convert ----------------
__global__ __launch_bounds__(256) void cvt_dual_k(const float* __restrict__ in,
                                                  float* __restrict__ outf,
                                                  unsigned short* __restrict__ outb, int n) {
  for (int i = blockIdx.x*256 + threadIdx.x; i < n; i += gridDim.x*256) {
    float v = in[i]; outf[i] = v; outb[i] = f2bf(v);
  }
}

// fp32 [K,N] -> bf16 [N,K] tiled transpose-convert
__global__ __launch_bounds__(256) void tcvt_k(const float* __restrict__ src,
                                              unsigned short* __restrict__ dst,
                                              int K, int N) {
  __shared__ float t[32][33];
  const int n0 = blockIdx.x*32, k0 = blockIdx.y*32;
  const int tx = threadIdx.x & 31, ty = threadIdx.x >> 5;
#pragma unroll
  for (int i = 0; i < 32; i += 8)
    t[ty+i][tx] = src[(size_t)(k0+ty+i)*N + n0+tx];
  __syncthreads();
#pragma unroll
  for (int i = 0; i < 32; i += 8)
    dst[(size_t)(n0+ty+i)*K + k0+tx] = f2bf(t[tx][ty+i]);
}

// concat 4x768 biases -> 3072
__global__ __launch_bounds__(256) void bcat_k(const float* __restrict__ a,
                                              const float* __restrict__ b,
                                              const float* __restrict__ c,
                                              const float* __restrict__ d,
                                              float* __restrict__ out) {
  int i = blockIdx.x*256 + threadIdx.x;   // 0..3071
  int w = i / 768;
  const float* s = (w == 0) ? a : (w == 1) ? b : (w == 2) ? c : d;
  out[i] = s[i - w*768];
}

// ---------------- 128^2 MFMA bf16 GEMM (R4 version, reverted) ----------------
// EPI: 0 bias; 1 bias+resid(fp32); 2 bias+exact gelu.  OBF: 1 -> bf16 out, 0 -> fp32 out.
// T1 XCD swizzle (FETCH 169->55MB measured). T3-minimal dbuf: issue next tile's
// gload_lds BEFORE compute, drain AFTER (one barrier/K-step). [R5's counted-vmcnt
// + swizzle additions were measured null -> reverted per regime gate.]
template<int EPI, int OBF>
__global__ __launch_bounds__(256, 3) void mgemm_k(
    const unsigned short* __restrict__ A,   // [M,K] bf16
    const unsigned short* __restrict__ Bw,  // [N,K] bf16 (pre-transposed weights)
    const float* __restrict__ bias,         // [N] fp32
    const float* __restrict__ resid,        // [M,N] fp32 (EPI==1)
    void* __restrict__ Cout, int M, int N, int K)
{
  __shared__ __align__(16) unsigned short As[2][128*32];
  __shared__ __align__(16) unsigned short Bs[2][128*32];
  const int nwg = gridDim.x * gridDim.y;
  int lin = blockIdx.y * gridDim.x + blockIdx.x;
  lin = (lin & 7) * (nwg >> 3) + (lin >> 3);
  const int bm = (lin / gridDim.x) * 128, bn = (lin % gridDim.x) * 128;
  const int tid = threadIdx.x;
  const int wave = tid >> 6, lane = tid & 63;
  const int wm = (wave >> 1)*64, wn = (wave & 1)*64;
  const int woff = wave*32*32;

  f32x4 acc[4][4] = {};

  const unsigned short* Ag = A  + (size_t)(bm + wave*32 + (lane>>2))*K + (lane&3)*8;
  const unsigned short* Bg = Bw + (size_t)(bn + wave*32 + (lane>>2))*K + (lane&3)*8;

  GLOAD_LDS(Ag,                As[0] + woff);
  GLOAD_LDS(Ag + 16*(size_t)K, As[0] + woff + 16*32);
  GLOAD_LDS(Bg,                Bs[0] + woff);
  GLOAD_LDS(Bg + 16*(size_t)K, Bs[0] + woff + 16*32);
  Ag += 32; Bg += 32;
  __syncthreads();

  const unsigned short* Ac = As[0]; unsigned short* An = As[1];
  const unsigned short* Bc = Bs[0]; unsigned short* Bn = Bs[1];
  const int nk = K >> 5;

#pragma unroll 1
  for (int t = 0; t < nk - 1; ++t) {
    GLOAD_LDS(Ag,                An + woff);
    GLOAD_LDS(Ag + 16*(size_t)K, An + woff + 16*32);
    GLOAD_LDS(Bg,                Bn + woff);
    GLOAD_LDS(Bg + 16*(size_t)K, Bn + woff + 16*32);
    Ag += 32; Bg += 32;

    short8 af[4], bfr[4];
#pragma unroll
    for (int i = 0; i < 4; ++i) {
      af[i]  = *(const short8*)&Ac[(wm + i*16 + (lane & 15))*32 + (lane >> 4)*8];
      bfr[i] = *(const short8*)&Bc[(wn + i*16 + (lane & 15))*32 + (lane >> 4)*8];
    }
    __builtin_amdgcn_s_setprio(1);
#pragma unroll
    for (int i = 0; i < 4; ++i)
#pragma unroll
      for (int j = 0; j < 4; ++j)
        acc[i][j] = __builtin_amdgcn_mfma_f32_16x16x32_bf16(af[i], bfr[j], acc[i][j], 0, 0, 0);
    __builtin_amdgcn_s_setprio(0);

    __syncthreads();
    const unsigned short* tA = Ac; Ac = An; An = (unsigned short*)tA;
    const unsigned short* tB = Bc; Bc = Bn; Bn = (unsigned short*)tB;
  }

  {
    short8 af[4], bfr[4];
#pragma unroll
    for (int i = 0; i < 4; ++i) {
      af[i]  = *(const short8*)&Ac[(wm + i*16 + (lane & 15))*32 + (lane >> 4)*8];
      bfr[i] = *(const short8*)&Bc[(wn + i*16 + (lane & 15))*32 + (lane >> 4)*8];
    }
#pragma unroll
    for (int i = 0; i < 4; ++i)
#pragma unroll
      for (int j = 0; j < 4; ++j)
        acc[i][j] = __builtin_amdgcn_mfma_f32_16x16x32_bf16(af[i], bfr[j], acc[i][j], 0, 0, 0);
  }

  const int col0 = bn + wn + (lane & 15);
  const int row0 = bm + wm + (lane >> 4)*4;
#pragma unroll
  for (int i = 0; i < 4; ++i) {
#pragma unroll
    for (int j = 0; j < 4; ++j) {
      const int n = col0 + j*16;
      const float bv = bias[n];
#pragma unroll
      for (int r = 0; r < 4; ++r) {
        const int m = row0 + i*16 + r;
        float v = acc[i][j][r] + bv;
        if (EPI == 1) v += resid[(size_t)m*N + n];
        if (EPI == 2) v = 0.5f*v*(1.0f + erff(v*0.70710678118654752f));
        if (OBF) ((unsigned short*)Cout)[(size_t)m*N + n] = f2bf(v);
        else     ((float*)Cout)[(size_t)m*N + n] = v;
      }
    }
  }
}

// ---------------- 256^2 8-phase MFMA GEMM (T3+T4+T5+T2, m201-style) -------------
// C[M,N] = A[M,K] @ Bw[N,K]^T + bias, bf16 out. EPI: 0 none, 2 exact gelu.
// 512 thr = 8 waves (2M x 4N); per-wave C = 128x64 (acc[8][4] f32x4).
// BK=64, LDS 128KB dbuf: A[2][256][64], B[2][256][64].
// Per K-tile, 4 phases; phase p: {ds_read A m-reps 2p,2p+1 (4xb128; ph0 also
// all 8 B-frags, held in regs) | stage 2 quarter-loads of NEXT tile | barrier |
// setprio(1) 16 MFMA setprio(0) | barrier}.
// Stage order per iter: ph0:Bq0,Bq1 ph1:Bq2,Bq3 ph2:Aq0,Aq2 ph3:Aq1,Aq3.
// Counted waits (never 0 in steady loop):
//  - ph1-end vmcnt(4): queue = {t:Aq1,Aq3}+{t+1:Bq0..3}=6 -> retires t's Aq1,Aq3
//    (read at ph2/ph3 of iter t).   [rows 64..127 of each wave-half]
//  - ph3-end vmcnt(2): queue = {t+1: 8 ops} -> retires Bq0..3 + Aq0,Aq2
//    (read at ph0/ph1 of iter t+1).
// LDS swizzle (both-sides, rule #21): pitch 128B => 16-row bank alias; store
// LDS[row][seg] = G[row][seg ^ 4*((row>>3)&1)] via per-lane PRE-SWIZZLED GLOBAL
// source (gload_lds dest stays linear); ds_read applies the same XOR -> rows
// 0-7 and 8-15 of a frag-read hit disjoint 16-bank halves (full 32-bank spread).
template<int EPI>
__global__ __launch_bounds__(512, 2) void mg256_k(
    const unsigned short* __restrict__ A,   // [M,K] bf16
    const unsigned short* __restrict__ Bw,  // [N,K] bf16
    const float* __restrict__ bias,         // [N] fp32
    unsigned short* __restrict__ Cout, int M, int N, int K)
{
  __shared__ __align__(16) unsigned short Ab[2][256*64];
  __shared__ __align__(16) unsigned short Bb[2][256*64];
  const int nwg = gridDim.x * gridDim.y;
  int lin = blockIdx.y * gridDim.x + blockIdx.x;
  lin = (lin & 7) * (nwg >> 3) + (lin >> 3);      // T1 XCD stripe (nwg%8==0)
  const int bm = (lin / gridDim.x) * 256, bn = (lin % gridDim.x) * 256;
  const int tid = threadIdx.x;
  const int wave = tid >> 6, lane = tid & 63;
  const int wr = wave >> 2, wc = wave & 3;
  const int fr = lane & 15, fg = lane >> 4;
  const int xsw = (fr & 8) ? 4 : 0;               // read-side seg XOR

  f32x4 acc[8][4] = {};
  short8 bfrag[4][2];

  // stage addressing: thread covers (row = q*64 + tid>>3, 16B seg = tid&7),
  // global col seg pre-swizzled: ^4 when (row>>3)&1 == wave&1
  const int srow = tid >> 3;
  const int sseg = (tid & 7) ^ ((wave & 1) << 2);
  const unsigned short* Asrc = A  + (size_t)(bm + srow)*K + sseg*8;
  const unsigned short* Bsrc = Bw + (size_t)(bn + srow)*K + sseg*8;
  const int ldst = wave * 512;                    // elems; + q*4096

#define MG_STGA(q, bf, kk) GLOAD_LDS(Asrc + (size_t)((q)*64)*K + (kk), &Ab[bf][(q)*4096 + ldst])
#define MG_STGB(q, bf, kk) GLOAD_LDS(Bsrc + (size_t)((q)*64)*K + (kk), &Bb[bf][(q)*4096 + ldst])

  const int arow0 = wr*128 + fr;
  const int brow0 = wc*64 + fr;
#define MG_A(m, s) (*(const short8*)&Ac[(arow0 + (m)*16)*64 + ((((s)*4) + fg) ^ xsw)*8])
#define MG_B(n, s) (*(const short8*)&Bc[(brow0 + (n)*16)*64 + ((((s)*4) + fg) ^ xsw)*8])

#define MG_MFMA(m0, a00, a01, a10, a11) do { \
    __builtin_amdgcn_s_setprio(1); \
    _Pragma("unroll") \
    for (int n = 0; n < 4; ++n) { \
      acc[m0][n]   = __builtin_amdgcn_mfma_f32_16x16x32_bf16(a00, bfrag[n][0], acc[m0][n],   0,0,0); \
      acc[m0][n]   = __builtin_amdgcn_mfma_f32_16x16x32_bf16(a01, bfrag[n][1], acc[m0][n],   0,0,0); \
      acc[m0+1][n] = __builtin_amdgcn_mfma_f32_16x16x32_bf16(a10, bfrag[n][0], acc[m0+1][n], 0,0,0); \
      acc[m0+1][n] = __builtin_amdgcn_mfma_f32_16x16x32_bf16(a11, bfrag[n][1], acc[m0+1][n], 0,0,0); \
    } \
    __builtin_amdgcn_s_setprio(0); } while (0)

  const int nk = K >> 6;   // 12 for K=768

  // ---- prologue: stage tile 0 in canonical op order ----
  MG_STGB(0, 0, 0); MG_STGB(1, 0, 0); MG_STGB(2, 0, 0); MG_STGB(3, 0, 0);
  MG_STGA(0, 0, 0); MG_STGA(2, 0, 0); MG_STGA(1, 0, 0); MG_STGA(3, 0, 0);
  asm volatile("s_waitcnt vmcnt(2)" ::: "memory");   // certify B0-3 + Aq0,Aq2
  __builtin_amdgcn_sched_barrier(0);
  __builtin_amdgcn_s_barrier();

  int cur = 0;
#pragma unroll 1
  for (int t = 0; t < nk - 1; ++t) {
    const int nx = cur ^ 1;
    const int kk = (t + 1) << 6;
    const unsigned short* Ac = Ab[cur];
    const unsigned short* Bc = Bb[cur];
    short8 x0, x1, y0, y1;
    // ---- ph0: B frags + A m0,1 ----
    x0 = MG_A(0,0); x1 = MG_A(0,1); y0 = MG_A(1,0); y1 = MG_A(1,1);
#pragma unroll
    for (int n = 0; n < 4; ++n) { bfrag[n][0] = MG_B(n,0); bfrag[n][1] = MG_B(n,1); }
    MG_STGB(0, nx, kk); MG_STGB(1, nx, kk);
    __builtin_amdgcn_s_barrier();
    MG_MFMA(0, x0, x1, y0, y1);
    __builtin_amdgcn_s_barrier();
    // ---- ph1: A m2,3 ----
    x0 = MG_A(2,0); x1 = MG_A(2,1); y0 = MG_A(3,0); y1 = MG_A(3,1);
    MG_STGB(2, nx, kk); MG_STGB(3, nx, kk);
    __builtin_amdgcn_s_barrier();
    MG_MFMA(2, x0, x1, y0, y1);
    asm volatile("s_waitcnt vmcnt(4)" ::: "memory");   // retire t: Aq1,Aq3
    __builtin_amdgcn_sched_barrier(0);
    __builtin_amdgcn_s_barrier();
    // ---- ph2: A m4,5 ----
    x0 = MG_A(4,0); x1 = MG_A(4,1); y0 = MG_A(5,0); y1 = MG_A(5,1);
    MG_STGA(0, nx, kk); MG_STGA(2, nx, kk);
    __builtin_amdgcn_s_barrier();
    MG_MFMA(4, x0, x1, y0, y1);
    __builtin_amdgcn_s_barrier();
    // ---- ph3: A m6,7 ----
    x0 = MG_A(6,0); x1 = MG_A(6,1); y0 = MG_A(7,0); y1 = MG_A(7,1);
    MG_STGA(1, nx, kk); MG_STGA(3, nx, kk);
    __builtin_amdgcn_s_barrier();
    MG_MFMA(6, x0, x1, y0, y1);
    asm volatile("s_waitcnt vmcnt(2)" ::: "memory");   // retire t+1: B0-3,Aq0,Aq2
    __builtin_amdgcn_sched_barrier(0);
    __builtin_amdgcn_s_barrier();
    cur = nx;
  }
  // ---- peeled last K-tile: no staging ----
  {
    const unsigned short* Ac = Ab[cur];
    const unsigned short* Bc = Bb[cur];
    short8 x0, x1, y0, y1;
    x0 = MG_A(0,0); x1 = MG_A(0,1); y0 = MG_A(1,0); y1 = MG_A(1,1);
#pragma unroll
    for (int n = 0; n < 4; ++n) { bfrag[n][0] = MG_B(n,0); bfrag[n][1] = MG_B(n,1); }
    __builtin_amdgcn_s_barrier();
    MG_MFMA(0, x0, x1, y0, y1);
    __builtin_amdgcn_s_barrier();
    x0 = MG_A(2,0); x1 = MG_A(2,1); y0 = MG_A(3,0); y1 = MG_A(3,1);
    __builtin_amdgcn_s_barrier();
    MG_MFMA(2, x0, x1, y0, y1);
    asm volatile("s_waitcnt vmcnt(0)" ::: "memory");   // retire last Aq1,Aq3
    __builtin_amdgcn_sched_barrier(0);
    __builtin_amdgcn_s_barrier();
    x0 = MG_A(4,0); x1 = MG_A(4,1); y0 = MG_A(5,0); y1 = MG_A(5,1);
    __builtin_amdgcn_s_barrier();
    MG_MFMA(4, x0, x1, y0, y1);
    __builtin_amdgcn_s_barrier();
    x0 = MG_A(6,0); x1 = MG_A(6,1); y0 = MG_A(7,0); y1 = MG_A(7,1);
    MG_MFMA(6, x0, x1, y0, y1);
  }
#undef MG_STGA
#undef MG_STGB
#undef MG_A
#undef MG_B
#undef MG_MFMA

  // ---- epilogue ----
  const int crow0 = bm + wr*128 + fg*4;
  const int ccol0 = bn + wc*64 + fr;
#pragma unroll
  for (int n = 0; n < 4; ++n) {
    const float bv = bias[ccol0 + n*16];
#pragma unroll
    for (int m = 0; m < 8; ++m) {
#pragma unroll
      for (int r = 0; r < 4; ++r) {
        float v = acc[m][n][r] + bv;
        if (EPI == 2) v = 0.5f*v*(1.0f + erff(v*0.70710678118654752f));
        Cout[(size_t)(crow0 + m*16 + r)*N + ccol0 + n*16] = f2bf(v);
      }
    }
  }
}

// ---------------- per-(b,h,s) reciprocal context-vector L2 norm ----------------
__global__ __launch_bounds__(256) void cnorm_k(const unsigned short* __restrict__ c,
                                               float* __restrict__ rn) {
  int idx = blockIdx.x*4 + (threadIdx.x >> 6);   // (b*NH + h)*SS + s
  int lane = threadIdx.x & 63;
  int s  = idx % SS;
  int bh = idx / SS;
  int h  = bh % NH;
  int b  = bh / NH;
  float v = bf2f(c[((size_t)(b*SS + s))*FF + h*DH + lane]);
  float ss = v*v;
#pragma unroll
  for (int off = 32; off; off >>= 1) ss += __shfl_xor(ss, off, 64);
  if (lane == 0) rn[idx] = rsqrtf(ss);   // store 1/||c||
}

// ---------------- V transpose: [b,s][h,d] (pitch FF) -> VT[bh][d][s] ----------------
__global__ __launch_bounds__(256) void vtrans_k(const unsigned short* __restrict__ v,
                                                unsigned short* __restrict__ VT) {
  __shared__ unsigned short t[64][72];
  const int s0 = blockIdx.x*64;
  const int h  = blockIdx.y;
  const int b  = blockIdx.z;
  const size_t base = (size_t)(b*SS)*FF + h*DH;
  const int row = threadIdx.x >> 2, seg = threadIdx.x & 3;
  const unsigned short* vg = v + base + (size_t)(s0+row)*FF + seg*16;
  *(uint4*)&t[row][seg*16]     = *(const uint4*)vg;
  *(uint4*)&t[row][seg*16 + 8] = *(const uint4*)(vg + 8);
  __syncthreads();
  unsigned short o[16];
#pragma unroll
  for (int u = 0; u < 16; ++u) o[u] = t[seg*16 + u][row];
  unsigned short* og = VT + ((size_t)(b*NH + h)*DH + row)*SS + s0 + seg*16;
  *(uint4*)og       = *(const uint4*)&o[0];
  *(uint4*)(og + 8) = *(const uint4*)&o[8];
}

// ---------------- pipelined MFMA dual-branch flash attention ----------------
__global__ __launch_bounds__(256, 3) void attn5_k(
    const unsigned short* __restrict__ q, const unsigned short* __restrict__ k,
    const unsigned short* __restrict__ c, const float* __restrict__ rn,
    const unsigned short* __restrict__ VT, unsigned short* __restrict__ ctxO)
{
  // bijective remap: bid = x + 8y + 96z in [0,1536)
  const int bid = blockIdx.x + 8*blockIdx.y + 96*blockIdx.z;
  const int l0  = ((bid >> 3) & 7) << 6;           // q-chunk
  const int bh  = (bid & 7) + ((bid >> 6) << 3);   // (b*NH+h), same-XCD group
  const int h   = bh % NH;
  const int b   = bh / NH;
  const int tid = threadIdx.x;
  const int wave = tid >> 6, lane = tid & 63;
  const int wm = wave * 16;
  const int fr = lane & 15;
  const int fg = lane >> 4;
  const size_t base   = (size_t)(b*SS)*FF + h*DH;
  const size_t vtbase = (size_t)bh*DH*SS;

  __shared__ __align__(16) unsigned short Ks [2][64*72];
  __shared__ __align__(16) unsigned short Crs[2][64*72];
  __shared__ __align__(16) unsigned short Ps [4][16*72];
  unsigned short* Pw = Ps[wave];

  const unsigned short* qrow = q + base + (size_t)(l0 + wm + fr)*FF + fg*8;
  const unsigned short* crow = c + base + (size_t)(l0 + wm + fr)*FF + fg*8;
  const short8 aQ0 = *(const short8*)qrow;
  const short8 aQ1 = *(const short8*)(qrow + 32);
  const short8 aC0 = *(const short8*)crow;
  const short8 aC1 = *(const short8*)(crow + 32);

  float rnl[4];
#pragma unroll
  for (int reg = 0; reg < 4; ++reg)
    rnl[reg] = rn[(size_t)bh*SS + l0 + wm + fg*4 + reg];

  const int srow = tid >> 2, sseg = tid & 3;
  {
    const unsigned short* kg = k + base + (size_t)srow*FF + sseg*16;
    const unsigned short* cg = c + base + (size_t)srow*FF + sseg*16;
    *(uint4*)&Ks [0][srow*72 + sseg*16]     = *(const uint4*)kg;
    *(uint4*)&Ks [0][srow*72 + sseg*16 + 8] = *(const uint4*)(kg + 8);
    *(uint4*)&Crs[0][srow*72 + sseg*16]     = *(const uint4*)cg;
    *(uint4*)&Crs[0][srow*72 + sseg*16 + 8] = *(const uint4*)(cg + 8);
  }
  __syncthreads();

  float rs2[4], rs1[4];
#pragma unroll
  for (int r = 0; r < 4; ++r) { rs2[r] = 0.f; rs1[r] = 0.f; }
  f32x4 oc1[4] = {}, oc2[4] = {};

#pragma unroll 1
  for (int it = 0; it < 8; ++it) {
    const int r0 = it*64;
    const int cur = it & 1, nxt = cur ^ 1;

    uint4 nk0, nk1, nc0, nc1;
    if (it < 7) {
      const unsigned short* kg = k + base + (size_t)(r0 + 64 + srow)*FF + sseg*16;
      const unsigned short* cg = c + base + (size_t)(r0 + 64 + srow)*FF + sseg*16;
      nk0 = *(const uint4*)kg;  nk1 = *(const uint4*)(kg + 8);
      nc0 = *(const uint4*)cg;  nc1 = *(const uint4*)(cg + 8);
    }

    float rnr[4];
    short8 bv0[4], bv1[4];
#pragma unroll
    for (int nt = 0; nt < 4; ++nt) {
      rnr[nt] = rn[(size_t)bh*SS + r0 + nt*16 + fr];
      const unsigned short* vtr = VT + vtbase + (size_t)(nt*16 + fr)*SS + r0 + fg*8;
      bv0[nt] = *(const short8*)vtr;
      bv1[nt] = *(const short8*)(vtr + 32);
    }

    f32x4 s1a[4] = {}, s2a[4] = {};
#pragma unroll
    for (int nt = 0; nt < 4; ++nt) {
      const short8 bK0 = *(const short8*)&Ks [cur][(nt*16+fr)*72 + fg*8];
      const short8 bK1 = *(const short8*)&Ks [cur][(nt*16+fr)*72 + fg*8 + 32];
      const short8 bC0 = *(const short8*)&Crs[cur][(nt*16+fr)*72 + fg*8];
      const short8 bC1 = *(const short8*)&Crs[cur][(nt*16+fr)*72 + fg*8 + 32];
      s2a[nt] = __builtin_amdgcn_mfma_f32_16x16x32_bf16(aQ0, bK0, s2a[nt], 0,0,0);
      s2a[nt] = __builtin_amdgcn_mfma_f32_16x16x32_bf16(aQ1, bK1, s2a[nt], 0,0,0);
      s1a[nt] = __builtin_amdgcn_mfma_f32_16x16x32_bf16(aC0, bC0, s1a[nt], 0,0,0);
      s1a[nt] = __builtin_amdgcn_mfma_f32_16x16x32_bf16(aC1, bC1, s1a[nt], 0,0,0);
    }

    float sv1[4][4], sv2[4][4];
#pragma unroll
    for (int nt = 0; nt < 4; ++nt)
#pragma unroll
      for (int reg = 0; reg < 4; ++reg) {
        const int ql = wm + fg*4 + reg;
        const int rr = nt*16 + fr;
        sv2[reg][nt] = s2a[nt][reg] * 0.125f;
        sv1[reg][nt] = 1.0f - s1a[nt][reg]*rnl[reg]*rnr[nt]
                     + ((l0+ql) == (r0+rr) ? 1.0f : 0.0f);
      }

#pragma unroll
    for (int reg = 0; reg < 4; ++reg) {
      const int prow = (fg*4 + reg)*72;
#pragma unroll
      for (int nt = 0; nt < 4; ++nt) {
        const float x1 = __expf(sv1[reg][nt] - 3.0f);
        Pw[prow + nt*16 + fr] = f2bf(x1);
        rs1[reg] += x1;
      }
    }
    {
      const short8 p0 = *(const short8*)&Pw[fr*72 + fg*8];
      const short8 p1 = *(const short8*)&Pw[fr*72 + fg*8 + 32];
#pragma unroll
      for (int nt = 0; nt < 4; ++nt) {
        oc1[nt] = __builtin_amdgcn_mfma_f32_16x16x32_bf16(p0, bv0[nt], oc1[nt], 0,0,0);
        oc1[nt] = __builtin_amdgcn_mfma_f32_16x16x32_bf16(p1, bv1[nt], oc1[nt], 0,0,0);
      }
    }

#pragma unroll
    for (int reg = 0; reg < 4; ++reg) {
      const int prow = (fg*4 + reg)*72;
#pragma unroll
      for (int nt = 0; nt < 4; ++nt) {
        const float x2 = __expf(sv2[reg][nt] - 3.0f);
        Pw[prow + nt*16 + fr] = f2bf(x2);
        rs2[reg] += x2;
      }
    }
    {
      const short8 p0 = *(const short8*)&Pw[fr*72 + fg*8];
      const short8 p1 = *(const short8*)&Pw[fr*72 + fg*8 + 32];
#pragma unroll
      for (int nt = 0; nt < 4; ++nt) {
        oc2[nt] = __builtin_amdgcn_mfma_f32_16x16x32_bf16(p0, bv0[nt], oc2[nt], 0,0,0);
        oc2[nt] = __builtin_amdgcn_mfma_f32_16x16x32_bf16(p1, bv1[nt], oc2[nt], 0,0,0);
      }
    }

    if (it < 7) {
      *(uint4*)&Ks [nxt][srow*72 + sseg*16]     = nk0;
      *(uint4*)&Ks [nxt][srow*72 + sseg*16 + 8] = nk1;
      *(uint4*)&Crs[nxt][srow*72 + sseg*16]     = nc0;
      *(uint4*)&Crs[nxt][srow*72 + sseg*16 + 8] = nc1;
    }
    __syncthreads();
  }

#pragma unroll
  for (int reg = 0; reg < 4; ++reg) {
    float t1 = rs1[reg], t2 = rs2[reg];
#pragma unroll
    for (int off = 1; off < 16; off <<= 1) {
      t1 += __shfl_xor(t1, off, 64);
      t2 += __shfl_xor(t2, off, 64);
    }
    const float i1 = 0.5f / t1;
    const float i2 = 0.5f / t2;
    const int prow = (fg*4 + reg)*72;
#pragma unroll
    for (int nt = 0; nt < 4; ++nt)
      Pw[prow + nt*16 + fr] = f2bf(oc1[nt][reg]*i1 + oc2[nt][reg]*i2);
  }
  {
    const int row = lane >> 2, seg = lane & 3;
    const int Mrow = b*SS + l0 + wm + row;
    unsigned short* og = ctxO + (size_t)Mrow*DD + h*DH + seg*16;
    *(uint4*)og       = *(const uint4*)&Pw[row*72 + seg*16];
    *(uint4*)(og + 8) = *(const uint4*)&Pw[row*72 + seg*16 + 8];
  }
}

// ---------------- row LayerNorm over D=768: in -> (outf fp32, outb bf16) ----------------
__global__ __launch_bounds__(256) void ln_k(const float* __restrict__ in,
                                            const float* __restrict__ g,
                                            const float* __restrict__ b,
                                            float* __restrict__ outf,
                                            unsigned short* __restrict__ outb) {
  __shared__ float xs[DD];
  __shared__ float red[4];
  const int tid = threadIdx.x;
  const float* xr = in + (size_t)blockIdx.x * DD;
  float* xo = outf + (size_t)blockIdx.x * DD;
  unsigned short* xbr = outb + (size_t)blockIdx.x * DD;
  float s = 0.f;
  for (int d = tid; d < DD; d += 256) { float v = xr[d]; xs[d] = v; s += v; }
#pragma unroll
  for (int off = 32; off; off >>= 1) s += __shfl_xor(s, off, 64);
  if ((tid & 63) == 0) red[tid >> 6] = s;
  __syncthreads();
  float mu = (red[0]+red[1]+red[2]+red[3]) * (1.f/DD);
  __syncthreads();
  float s2 = 0.f;
  for (int d = tid; d < DD; d += 256) { float t = xs[d]-mu; s2 += t*t; }
#pragma unroll
  for (int off = 32; off; off >>= 1) s2 += __shfl_xor(s2, off, 64);
  if ((tid & 63) == 0) red[tid >> 6] = s2;
  __syncthreads();
  float var = (red[0]+red[1]+red[2]+red[3]) * (1.f/DD);
  float rstd = rsqrtf(var + 1e-12f);
  for (int d = tid; d < DD; d += 256) {
    float o = (xs[d]-mu)*rstd*g[d] + b[d];
    xo[d] = o;
    xbr[d] = f2bf(o);
  }
}

// ---------------- launcher ----------------
extern "C" void kernel_launch(void* const* d_in, const int* in_sizes, int n_in,
                              void* d_out, int out_size, void* d_ws, size_t ws_size,
                              hipStream_t stream) {
  const float* hs  = (const float*)d_in[0];
  const float* Wq  = (const float*)d_in[1];  const float* bq  = (const float*)d_in[2];
  const float* Wk  = (const float*)d_in[3];  const float* bk  = (const float*)d_in[4];
  const float* Wv  = (const float*)d_in[5];  const float* bv  = (const float*)d_in[6];
  const float* Wc  = (const float*)d_in[7];  const float* bc  = (const float*)d_in[8];
  const float* Wo  = (const float*)d_in[9];  const float* bo  = (const float*)d_in[10];
  const float* g1  = (const float*)d_in[11]; const float* b1  = (const float*)d_in[12];
  const float* Wi  = (const float*)d_in[13]; const float* bi  = (const float*)d_in[14];
  const float* Wo2 = (const float*)d_in[15]; const float* bo2 = (const float*)d_in[16];
  const float* g2  = (const float*)d_in[17]; const float* b2  = (const float*)d_in[18];

  const size_t XN  = (size_t)MM * DD;       // 6,291,456
  const size_t HN  = (size_t)MM * FF;       // 25,165,824
  const int    nBH = BB*NH*SS;              // 98304
  const size_t WTN = 7667712;               // per-layer transposed weights (elems)

  char* p = (char*)d_ws;
  float*          x      = (float*)p;           p += XN*4;
  float*          attnf  = (float*)p;           p += XN*4;
  unsigned short* qkvc16 = (unsigned short*)p;  p += HN*2;   // also hb16 (aliased)
  unsigned short* xb16   = (unsigned short*)p;  p += XN*2;
  unsigned short* ctx16  = (unsigned short*)p;  p += XN*2;
  unsigned short* attn16 = (unsigned short*)p;  p += XN*2;
  unsigned short* vt16   = (unsigned short*)p;  p += XN*2;   // V^T [bh][d][s]
  unsigned short* WT     = (unsigned short*)p;  p += WTN*2;
  float*          bqkvc  = (float*)p;           p += 3072*4;
  float*          cnb    = (float*)p;           p += (size_t)nBH*4;
  const size_t need = (size_t)(p - (char*)d_ws);
  if (ws_size < need) return;

  unsigned short* WqkvcT = WT;                    // [3072][768]
  unsigned short* WoT    = WT + 2359296;          // [768][768]
  unsigned short* WiT    = WT + 2949120;          // [3072][768]
  unsigned short* Wo2T   = WT + 5308416;          // [768][3072]
  unsigned short* hb16   = qkvc16;                // FFN intermediate aliases QKVC

  cvt_dual_k<<<4096, 256, 0, stream>>>(hs, x, xb16, (int)XN);

  dim3 gG2(FF/256, MM/256);   // 12 x 32  (QKVC, Wi — 256^2 8-phase)
  dim3 gGD(DD/128, MM/128);   // 6  x 64  (Wo, Wo2 — 128^2)
  dim3 gA(SS/64, NH, BB);     // 8 x 12 x 16 = 1536
  dim3 tDD(DD/32, DD/32);     // 24 x 24
  dim3 tDF(FF/32, DD/32);     // 96 x 24  (src [D,F])
  dim3 tFD(DD/32, FF/32);     // 24 x 96  (src [F,D])

  for (int i = 0; i < NL; ++i) {
    const size_t wD = (size_t)i*DD*DD, wF = (size_t)i*DD*FF;
    tcvt_k<<<tDD, 256, 0, stream>>>(Wq + wD, WqkvcT,            DD, DD);
    tcvt_k<<<tDD, 256, 0, stream>>>(Wk + wD, WqkvcT +  768*768, DD, DD);
    tcvt_k<<<tDD, 256, 0, stream>>>(Wv + wD, WqkvcT + 1536*768, DD, DD);
    tcvt_k<<<tDD, 256, 0, stream>>>(Wc + wD, WqkvcT + 2304*768, DD, DD);
    tcvt_k<<<tDD, 256, 0, stream>>>(Wo + wD, WoT,  DD, DD);
    tcvt_k<<<tDF, 256, 0, stream>>>(Wi + wF, WiT,  DD, FF);
    tcvt_k<<<tFD, 256, 0, stream>>>(Wo2 + wF, Wo2T, FF, DD);
    bcat_k<<<12, 256, 0, stream>>>(bq + (size_t)i*DD, bk + (size_t)i*DD,
                                   bv + (size_t)i*DD, bc + (size_t)i*DD, bqkvc);

    // fused QKVC projection: [8192,768] @ [768,3072] -> bf16 [8192,3072]
    mg256_k<0><<<gG2, 512, 0, stream>>>(xb16, WqkvcT, bqkvc, qkvc16, MM, FF, DD);

    cnorm_k<<<nBH/4, 256, 0, stream>>>(qkvc16 + 2304, cnb);
    vtrans_k<<<gA, 256, 0, stream>>>(qkvc16 + 1536, vt16);
    attn5_k<<<gA, 256, 0, stream>>>(qkvc16, qkvc16 + 768, qkvc16 + 2304,
                                    cnb, vt16, ctx16);

    // attn_out = LN1(ctx @ Wo + bo + x)
    mgemm_k<1,0><<<gGD, 256, 0, stream>>>(ctx16, WoT, bo + (size_t)i*DD, x, attnf, MM, DD, DD);
    ln_k<<<MM, 256, 0, stream>>>(attnf, g1 + (size_t)i*DD, b1 + (size_t)i*DD, attnf, attn16);

    // h = gelu(attn @ Wi + bi) -> bf16 (overwrites dead qkvc16)
    mg256_k<2><<<gG2, 512, 0, stream>>>(attn16, WiT, bi + (size_t)i*FF, hb16, MM, FF, DD);
    // x = LN2(h @ Wo2 + bo2 + attn); final layer writes fp32 straight to d_out
    mgemm_k<1,0><<<gGD, 256, 0, stream>>>(hb16, Wo2T, bo2 + (size_t)i*DD, attnf, x, MM, DD, FF);
    float* lnout = (i == NL-1) ? (float*)d_out : x;
    ln_k<<<MM, 256, 0, stream>>>(x, g2 + (size_t)i*DD, b2 + (size_t)i*DD, lnout, xb16);
  }
}

// Round 7
// 1506.306 us; speedup vs baseline: 1.0387x; 1.0387x over previous
//
#include <hip/hip_runtime.h>
#include <math.h>

#define DD 768
#define FF 3072
#define SS 512
#define BB 16
#define NH 12
#define DH 64
#define NL 4
#define MM (BB*SS)   // 8192

typedef __attribute__((ext_vector_type(8))) short short8;
typedef __attribute__((ext_vector_type(4))) float f32x4;

__device__ __forceinline__ unsigned short f2bf(float f) {
  unsigned u = __float_as_uint(f);
  return (unsigned short)((u + 0x7FFFu + ((u >> 16) & 1u)) >> 16);
}
__device__ __forceinline__ float bf2f(unsigned short s) {
  return __uint_as_float(((unsigned)s) << 16);
}
// raw v_exp_f32: computes 2^x (one transcendental op, no wrapper mul)
__device__ __forceinline__ float fexp2(float x) {
  float r; asm("v_exp_f32 %0, %1" : "=v"(r) : "v"(x)); return r;
}

#define GLOAD_LDS(g, l) \
  __builtin_amdgcn_global_load_lds((const __attribute__((address_space(1))) void*)(g), \
                                   (__attribute__((address_space(3))) void*)(l), 16, 0, 0)

// ---------------- convert ----------------
__global__ __launch_bounds__(256) void cvt_dual_k(const float* __restrict__ in,
                                                  float* __restrict__ outf,
                                                  unsigned short* __restrict__ outb, int n) {
  for (int i = blockIdx.x*256 + threadIdx.x; i < n; i += gridDim.x*256) {
    float v = in[i]; outf[i] = v; outb[i] = f2bf(v);
  }
}

// fp32 [K,N] -> bf16 [N,K] tiled transpose-convert
__global__ __launch_bounds__(256) void tcvt_k(const float* __restrict__ src,
                                              unsigned short* __restrict__ dst,
                                              int K, int N) {
  __shared__ float t[32][33];
  const int n0 = blockIdx.x*32, k0 = blockIdx.y*32;
  const int tx = threadIdx.x & 31, ty = threadIdx.x >> 5;
#pragma unroll
  for (int i = 0; i < 32; i += 8)
    t[ty+i][tx] = src[(size_t)(k0+ty+i)*N + n0+tx];
  __syncthreads();
#pragma unroll
  for (int i = 0; i < 32; i += 8)
    dst[(size_t)(n0+ty+i)*K + k0+tx] = f2bf(t[tx][ty+i]);
}

// concat 4x768 biases -> 3072
__global__ __launch_bounds__(256) void bcat_k(const float* __restrict__ a,
                                              const float* __restrict__ b,
                                              const float* __restrict__ c,
                                              const float* __restrict__ d,
                                              float* __restrict__ out) {
  int i = blockIdx.x*256 + threadIdx.x;   // 0..3071
  int w = i / 768;
  const float* s = (w == 0) ? a : (w == 1) ? b : (w == 2) ? c : d;
  out[i] = s[i - w*768];
}

// ---------------- 128^2 MFMA bf16 GEMM (R4 structure, occupancy bumped) ---------
// EPI: 0 bias; 1 bias+resid(fp32); 2 bias+exact gelu.  OBF: 1 -> bf16 out, 0 -> fp32.
// T1 XCD swizzle (FETCH 169->55MB measured R3). T3-minimal dbuf: issue next
// tile's gload_lds BEFORE compute, drain AFTER (one barrier/K-step; measured
// 83.7->73.3us R4). R5 counted-vmcnt + LDS swizzle: measured null -> reverted.
// R6 256^2 8-phase: measured regression (1 blk/CU) -> reverted.
// (256,4): ~120 unified regs + 32KB LDS both fit 4 blocks/CU; R4's (256,3)
// left occupancy at 31% -- ask for 16 waves/CU to cover the barrier drain.
template<int EPI, int OBF>
__global__ __launch_bounds__(256, 4) void mgemm_k(
    const unsigned short* __restrict__ A,   // [M,K] bf16
    const unsigned short* __restrict__ Bw,  // [N,K] bf16 (pre-transposed weights)
    const float* __restrict__ bias,         // [N] fp32
    const float* __restrict__ resid,        // [M,N] fp32 (EPI==1)
    void* __restrict__ Cout, int M, int N, int K)
{
  __shared__ __align__(16) unsigned short As[2][128*32];
  __shared__ __align__(16) unsigned short Bs[2][128*32];
  const int nwg = gridDim.x * gridDim.y;
  int lin = blockIdx.y * gridDim.x + blockIdx.x;
  lin = (lin & 7) * (nwg >> 3) + (lin >> 3);
  const int bm = (lin / gridDim.x) * 128, bn = (lin % gridDim.x) * 128;
  const int tid = threadIdx.x;
  const int wave = tid >> 6, lane = tid & 63;
  const int wm = (wave >> 1)*64, wn = (wave & 1)*64;
  const int woff = wave*32*32;

  f32x4 acc[4][4] = {};

  const unsigned short* Ag = A  + (size_t)(bm + wave*32 + (lane>>2))*K + (lane&3)*8;
  const unsigned short* Bg = Bw + (size_t)(bn + wave*32 + (lane>>2))*K + (lane&3)*8;

  GLOAD_LDS(Ag,                As[0] + woff);
  GLOAD_LDS(Ag + 16*(size_t)K, As[0] + woff + 16*32);
  GLOAD_LDS(Bg,                Bs[0] + woff);
  GLOAD_LDS(Bg + 16*(size_t)K, Bs[0] + woff + 16*32);
  Ag += 32; Bg += 32;
  __syncthreads();

  const unsigned short* Ac = As[0]; unsigned short* An = As[1];
  const unsigned short* Bc = Bs[0]; unsigned short* Bn = Bs[1];
  const int nk = K >> 5;

#pragma unroll 1
  for (int t = 0; t < nk - 1; ++t) {
    GLOAD_LDS(Ag,                An + woff);
    GLOAD_LDS(Ag + 16*(size_t)K, An + woff + 16*32);
    GLOAD_LDS(Bg,                Bn + woff);
    GLOAD_LDS(Bg + 16*(size_t)K, Bn + woff + 16*32);
    Ag += 32; Bg += 32;

    short8 af[4], bfr[4];
#pragma unroll
    for (int i = 0; i < 4; ++i) {
      af[i]  = *(const short8*)&Ac[(wm + i*16 + (lane & 15))*32 + (lane >> 4)*8];
      bfr[i] = *(const short8*)&Bc[(wn + i*16 + (lane & 15))*32 + (lane >> 4)*8];
    }
    __builtin_amdgcn_s_setprio(1);
#pragma unroll
    for (int i = 0; i < 4; ++i)
#pragma unroll
      for (int j = 0; j < 4; ++j)
        acc[i][j] = __builtin_amdgcn_mfma_f32_16x16x32_bf16(af[i], bfr[j], acc[i][j], 0, 0, 0);
    __builtin_amdgcn_s_setprio(0);

    __syncthreads();
    const unsigned short* tA = Ac; Ac = An; An = (unsigned short*)tA;
    const unsigned short* tB = Bc; Bc = Bn; Bn = (unsigned short*)tB;
  }

  {
    short8 af[4], bfr[4];
#pragma unroll
    for (int i = 0; i < 4; ++i) {
      af[i]  = *(const short8*)&Ac[(wm + i*16 + (lane & 15))*32 + (lane >> 4)*8];
      bfr[i] = *(const short8*)&Bc[(wn + i*16 + (lane & 15))*32 + (lane >> 4)*8];
    }
#pragma unroll
    for (int i = 0; i < 4; ++i)
#pragma unroll
      for (int j = 0; j < 4; ++j)
        acc[i][j] = __builtin_amdgcn_mfma_f32_16x16x32_bf16(af[i], bfr[j], acc[i][j], 0, 0, 0);
  }

  const int col0 = bn + wn + (lane & 15);
  const int row0 = bm + wm + (lane >> 4)*4;
#pragma unroll
  for (int i = 0; i < 4; ++i) {
#pragma unroll
    for (int j = 0; j < 4; ++j) {
      const int n = col0 + j*16;
      const float bv = bias[n];
#pragma unroll
      for (int r = 0; r < 4; ++r) {
        const int m = row0 + i*16 + r;
        float v = acc[i][j][r] + bv;
        if (EPI == 1) v += resid[(size_t)m*N + n];
        if (EPI == 2) v = 0.5f*v*(1.0f + erff(v*0.70710678118654752f));
        if (OBF) ((unsigned short*)Cout)[(size_t)m*N + n] = f2bf(v);
        else     ((float*)Cout)[(size_t)m*N + n] = v;
      }
    }
  }
}

// ---------------- per-(b,h,s) reciprocal context-vector L2 norm ----------------
__global__ __launch_bounds__(256) void cnorm_k(const unsigned short* __restrict__ c,
                                               float* __restrict__ rn) {
  int idx = blockIdx.x*4 + (threadIdx.x >> 6);   // (b*NH + h)*SS + s
  int lane = threadIdx.x & 63;
  int s  = idx % SS;
  int bh = idx / SS;
  int h  = bh % NH;
  int b  = bh / NH;
  float v = bf2f(c[((size_t)(b*SS + s))*FF + h*DH + lane]);
  float ss = v*v;
#pragma unroll
  for (int off = 32; off; off >>= 1) ss += __shfl_xor(ss, off, 64);
  if (lane == 0) rn[idx] = rsqrtf(ss);   // store 1/||c||
}

// ---------------- V transpose: [b,s][h,d] (pitch FF) -> VT[bh][d][s] ----------------
__global__ __launch_bounds__(256) void vtrans_k(const unsigned short* __restrict__ v,
                                                unsigned short* __restrict__ VT) {
  __shared__ unsigned short t[64][72];
  const int s0 = blockIdx.x*64;
  const int h  = blockIdx.y;
  const int b  = blockIdx.z;
  const size_t base = (size_t)(b*SS)*FF + h*DH;
  const int row = threadIdx.x >> 2, seg = threadIdx.x & 3;
  const unsigned short* vg = v + base + (size_t)(s0+row)*FF + seg*16;
  *(uint4*)&t[row][seg*16]     = *(const uint4*)vg;
  *(uint4*)&t[row][seg*16 + 8] = *(const uint4*)(vg + 8);
  __syncthreads();
  unsigned short o[16];
#pragma unroll
  for (int u = 0; u < 16; ++u) o[u] = t[seg*16 + u][row];
  unsigned short* og = VT + ((size_t)(b*NH + h)*DH + row)*SS + s0 + seg*16;
  *(uint4*)og       = *(const uint4*)&o[0];
  *(uint4*)(og + 8) = *(const uint4*)&o[8];
}

// ---------------- pipelined MFMA dual-branch flash attention ----------------
// Block: (64 q-rows, h, b), 4 waves x 16 q-rows. K/C tiles in padded LDS,
// register-double-buffered staging; one barrier per iter. Fixed softmax offsets
// both branches (bounded scores; offset cancels in normalization).
// exp via raw v_exp_f32 (2^x) with log2e folded into scales/offsets at load:
//   x1 = 2^((eye-2)*L - s1*(rnl*L)*rnr),  x2 = 2^(s2*(0.125*L) - 3L).
// XCD swizzle: 8 q-blocks of one (b,h) share an XCD's L2.
__global__ __launch_bounds__(256, 3) void attn5_k(
    const unsigned short* __restrict__ q, const unsigned short* __restrict__ k,
    const unsigned short* __restrict__ c, const float* __restrict__ rn,
    const unsigned short* __restrict__ VT, unsigned short* __restrict__ ctxO)
{
  // bijective remap: bid = x + 8y + 96z in [0,1536)
  const int bid = blockIdx.x + 8*blockIdx.y + 96*blockIdx.z;
  const int l0  = ((bid >> 3) & 7) << 6;           // q-chunk
  const int bh  = (bid & 7) + ((bid >> 6) << 3);   // (b*NH+h), same-XCD group
  const int h   = bh % NH;
  const int b   = bh / NH;
  const int tid = threadIdx.x;
  const int wave = tid >> 6, lane = tid & 63;
  const int wm = wave * 16;
  const int fr = lane & 15;     // frag row (A/B) / col (C,D)
  const int fg = lane >> 4;     // k-group (A/B) / row-quad (C,D)
  const size_t base   = (size_t)(b*SS)*FF + h*DH;
  const size_t vtbase = (size_t)bh*DH*SS;

  const float L2E = 1.4426950408889634f;

  __shared__ __align__(16) unsigned short Ks [2][64*72];
  __shared__ __align__(16) unsigned short Crs[2][64*72];
  __shared__ __align__(16) unsigned short Ps [4][16*72];
  unsigned short* Pw = Ps[wave];

  // loop-invariant A-frags straight from global (16B contiguous)
  const unsigned short* qrow = q + base + (size_t)(l0 + wm + fr)*FF + fg*8;
  const unsigned short* crow = c + base + (size_t)(l0 + wm + fr)*FF + fg*8;
  const short8 aQ0 = *(const short8*)qrow;
  const short8 aQ1 = *(const short8*)(qrow + 32);
  const short8 aC0 = *(const short8*)crow;
  const short8 aC1 = *(const short8*)(crow + 32);

  float rnlL[4];   // rnl * log2e (folded)
#pragma unroll
  for (int reg = 0; reg < 4; ++reg)
    rnlL[reg] = rn[(size_t)bh*SS + l0 + wm + fg*4 + reg] * L2E;

  // ---- stage tile 0 (rows 0..63) ----
  const int srow = tid >> 2, sseg = tid & 3;      // 4 threads/row, 32B each
  {
    const unsigned short* kg = k + base + (size_t)srow*FF + sseg*16;
    const unsigned short* cg = c + base + (size_t)srow*FF + sseg*16;
    *(uint4*)&Ks [0][srow*72 + sseg*16]     = *(const uint4*)kg;
    *(uint4*)&Ks [0][srow*72 + sseg*16 + 8] = *(const uint4*)(kg + 8);
    *(uint4*)&Crs[0][srow*72 + sseg*16]     = *(const uint4*)cg;
    *(uint4*)&Crs[0][srow*72 + sseg*16 + 8] = *(const uint4*)(cg + 8);
  }
  __syncthreads();

  float rs2[4], rs1[4];
#pragma unroll
  for (int r = 0; r < 4; ++r) { rs2[r] = 0.f; rs1[r] = 0.f; }
  f32x4 oc1[4] = {}, oc2[4] = {};

#pragma unroll 1
  for (int it = 0; it < 8; ++it) {
    const int r0 = it*64;
    const int cur = it & 1, nxt = cur ^ 1;

    // ---- prefetch next K/C tile into registers ----
    uint4 nk0, nk1, nc0, nc1;
    if (it < 7) {
      const unsigned short* kg = k + base + (size_t)(r0 + 64 + srow)*FF + sseg*16;
      const unsigned short* cg = c + base + (size_t)(r0 + 64 + srow)*FF + sseg*16;
      nk0 = *(const uint4*)kg;  nk1 = *(const uint4*)(kg + 8);
      nc0 = *(const uint4*)cg;  nc1 = *(const uint4*)(cg + 8);
    }

    // ---- prefetch rnr + VT frags (issue early) ----
    float rnr[4];
    short8 bv0[4], bv1[4];
#pragma unroll
    for (int nt = 0; nt < 4; ++nt) {
      rnr[nt] = rn[(size_t)bh*SS + r0 + nt*16 + fr];
      const unsigned short* vtr = VT + vtbase + (size_t)(nt*16 + fr)*SS + r0 + fg*8;
      bv0[nt] = *(const short8*)vtr;
      bv1[nt] = *(const short8*)(vtr + 32);
    }

    // ---- dual scores via MFMA from staged LDS ----
    f32x4 s1a[4] = {}, s2a[4] = {};
#pragma unroll
    for (int nt = 0; nt < 4; ++nt) {
      const short8 bK0 = *(const short8*)&Ks [cur][(nt*16+fr)*72 + fg*8];
      const short8 bK1 = *(const short8*)&Ks [cur][(nt*16+fr)*72 + fg*8 + 32];
      const short8 bC0 = *(const short8*)&Crs[cur][(nt*16+fr)*72 + fg*8];
      const short8 bC1 = *(const short8*)&Crs[cur][(nt*16+fr)*72 + fg*8 + 32];
      s2a[nt] = __builtin_amdgcn_mfma_f32_16x16x32_bf16(aQ0, bK0, s2a[nt], 0,0,0);
      s2a[nt] = __builtin_amdgcn_mfma_f32_16x16x32_bf16(aQ1, bK1, s2a[nt], 0,0,0);
      s1a[nt] = __builtin_amdgcn_mfma_f32_16x16x32_bf16(aC0, bC0, s1a[nt], 0,0,0);
      s1a[nt] = __builtin_amdgcn_mfma_f32_16x16x32_bf16(aC1, bC1, s1a[nt], 0,0,0);
    }

    // ---- exp2 arguments; D-layout: row = wm+fg*4+reg, col = nt*16+fr ----
    float sv1[4][4], sv2[4][4];   // [reg][nt]
#pragma unroll
    for (int nt = 0; nt < 4; ++nt)
#pragma unroll
      for (int reg = 0; reg < 4; ++reg) {
        const int ql = wm + fg*4 + reg;
        const int rr = nt*16 + fr;
        sv2[reg][nt] = fmaf(s2a[nt][reg], 0.18033688011112042f, -4.328085122666890f);
        const float cc = ((l0+ql) == (r0+rr)) ? -1.4426950408889634f
                                              : -2.885390081777927f;
        sv1[reg][nt] = fmaf(-s1a[nt][reg], rnlL[reg]*rnr[nt], cc);
      }

    // ---- branch 1: P -> LDS -> frags -> PV1 ----
#pragma unroll
    for (int reg = 0; reg < 4; ++reg) {
      const int prow = (fg*4 + reg)*72;
#pragma unroll
      for (int nt = 0; nt < 4; ++nt) {
        const float x1 = fexp2(sv1[reg][nt]);
        Pw[prow + nt*16 + fr] = f2bf(x1);
        rs1[reg] += x1;
      }
    }
    {
      const short8 p0 = *(const short8*)&Pw[fr*72 + fg*8];
      const short8 p1 = *(const short8*)&Pw[fr*72 + fg*8 + 32];
#pragma unroll
      for (int nt = 0; nt < 4; ++nt) {
        oc1[nt] = __builtin_amdgcn_mfma_f32_16x16x32_bf16(p0, bv0[nt], oc1[nt], 0,0,0);
        oc1[nt] = __builtin_amdgcn_mfma_f32_16x16x32_bf16(p1, bv1[nt], oc1[nt], 0,0,0);
      }
    }

    // ---- branch 2 (same buffer, WAR via in-order DS) -> PV2 ----
#pragma unroll
    for (int reg = 0; reg < 4; ++reg) {
      const int prow = (fg*4 + reg)*72;
#pragma unroll
      for (int nt = 0; nt < 4; ++nt) {
        const float x2 = fexp2(sv2[reg][nt]);
        Pw[prow + nt*16 + fr] = f2bf(x2);
        rs2[reg] += x2;
      }
    }
    {
      const short8 p0 = *(const short8*)&Pw[fr*72 + fg*8];
      const short8 p1 = *(const short8*)&Pw[fr*72 + fg*8 + 32];
#pragma unroll
      for (int nt = 0; nt < 4; ++nt) {
        oc2[nt] = __builtin_amdgcn_mfma_f32_16x16x32_bf16(p0, bv0[nt], oc2[nt], 0,0,0);
        oc2[nt] = __builtin_amdgcn_mfma_f32_16x16x32_bf16(p1, bv1[nt], oc2[nt], 0,0,0);
      }
    }

    // ---- commit prefetched tile to the other LDS buffer ----
    if (it < 7) {
      *(uint4*)&Ks [nxt][srow*72 + sseg*16]     = nk0;
      *(uint4*)&Ks [nxt][srow*72 + sseg*16 + 8] = nk1;
      *(uint4*)&Crs[nxt][srow*72 + sseg*16]     = nc0;
      *(uint4*)&Crs[nxt][srow*72 + sseg*16 + 8] = nc1;
    }
    __syncthreads();
  }

  // ---- final cross-lane sum reduce + blend; stage in P buffer, coalesced store ----
#pragma unroll
  for (int reg = 0; reg < 4; ++reg) {
    float t1 = rs1[reg], t2 = rs2[reg];
#pragma unroll
    for (int off = 1; off < 16; off <<= 1) {
      t1 += __shfl_xor(t1, off, 64);
      t2 += __shfl_xor(t2, off, 64);
    }
    const float i1 = 0.5f / t1;
    const float i2 = 0.5f / t2;
    const int prow = (fg*4 + reg)*72;
#pragma unroll
    for (int nt = 0; nt < 4; ++nt)
      Pw[prow + nt*16 + fr] = f2bf(oc1[nt][reg]*i1 + oc2[nt][reg]*i2);
  }
  {
    // 4 lanes per row, 2x16B each -> one full 128B line per row
    const int row = lane >> 2, seg = lane & 3;
    const int Mrow = b*SS + l0 + wm + row;
    unsigned short* og = ctxO + (size_t)Mrow*DD + h*DH + seg*16;
    *(uint4*)og       = *(const uint4*)&Pw[row*72 + seg*16];
    *(uint4*)(og + 8) = *(const uint4*)&Pw[row*72 + seg*16 + 8];
  }
}

// ---------------- row LayerNorm over D=768: in -> (outf fp32, outb bf16) ----------------
__global__ __launch_bounds__(256) void ln_k(const float* __restrict__ in,
                                            const float* __restrict__ g,
                                            const float* __restrict__ b,
                                            float* __restrict__ outf,
                                            unsigned short* __restrict__ outb) {
  __shared__ float xs[DD];
  __shared__ float red[4];
  const int tid = threadIdx.x;
  const float* xr = in + (size_t)blockIdx.x * DD;
  float* xo = outf + (size_t)blockIdx.x * DD;
  unsigned short* xbr = outb + (size_t)blockIdx.x * DD;
  float s = 0.f;
  for (int d = tid; d < DD; d += 256) { float v = xr[d]; xs[d] = v; s += v; }
#pragma unroll
  for (int off = 32; off; off >>= 1) s += __shfl_xor(s, off, 64);
  if ((tid & 63) == 0) red[tid >> 6] = s;
  __syncthreads();
  float mu = (red[0]+red[1]+red[2]+red[3]) * (1.f/DD);
  __syncthreads();
  float s2 = 0.f;
  for (int d = tid; d < DD; d += 256) { float t = xs[d]-mu; s2 += t*t; }
#pragma unroll
  for (int off = 32; off; off >>= 1) s2 += __shfl_xor(s2, off, 64);
  if ((tid & 63) == 0) red[tid >> 6] = s2;
  __syncthreads();
  float var = (red[0]+red[1]+red[2]+red[3]) * (1.f/DD);
  float rstd = rsqrtf(var + 1e-12f);
  for (int d = tid; d < DD; d += 256) {
    float o = (xs[d]-mu)*rstd*g[d] + b[d];
    xo[d] = o;
    xbr[d] = f2bf(o);
  }
}

// ---------------- launcher ----------------
extern "C" void kernel_launch(void* const* d_in, const int* in_sizes, int n_in,
                              void* d_out, int out_size, void* d_ws, size_t ws_size,
                              hipStream_t stream) {
  const float* hs  = (const float*)d_in[0];
  const float* Wq  = (const float*)d_in[1];  const float* bq  = (const float*)d_in[2];
  const float* Wk  = (const float*)d_in[3];  const float* bk  = (const float*)d_in[4];
  const float* Wv  = (const float*)d_in[5];  const float* bv  = (const float*)d_in[6];
  const float* Wc  = (const float*)d_in[7];  const float* bc  = (const float*)d_in[8];
  const float* Wo  = (const float*)d_in[9];  const float* bo  = (const float*)d_in[10];
  const float* g1  = (const float*)d_in[11]; const float* b1  = (const float*)d_in[12];
  const float* Wi  = (const float*)d_in[13]; const float* bi  = (const float*)d_in[14];
  const float* Wo2 = (const float*)d_in[15]; const float* bo2 = (const float*)d_in[16];
  const float* g2  = (const float*)d_in[17]; const float* b2  = (const float*)d_in[18];

  const size_t XN  = (size_t)MM * DD;       // 6,291,456
  const size_t HN  = (size_t)MM * FF;       // 25,165,824
  const int    nBH = BB*NH*SS;              // 98304
  const size_t WTN = 7667712;               // per-layer transposed weights (elems)

  char* p = (char*)d_ws;
  float*          x      = (float*)p;           p += XN*4;
  float*          attnf  = (float*)p;           p += XN*4;
  unsigned short* qkvc16 = (unsigned short*)p;  p += HN*2;   // also hb16 (aliased)
  unsigned short* xb16   = (unsigned short*)p;  p += XN*2;
  unsigned short* ctx16  = (unsigned short*)p;  p += XN*2;
  unsigned short* attn16 = (unsigned short*)p;  p += XN*2;
  unsigned short* vt16   = (unsigned short*)p;  p += XN*2;   // V^T [bh][d][s]
  unsigned short* WT     = (unsigned short*)p;  p += WTN*2;
  float*          bqkvc  = (float*)p;           p += 3072*4;
  float*          cnb    = (float*)p;           p += (size_t)nBH*4;
  const size_t need = (size_t)(p - (char*)d_ws);
  if (ws_size < need) return;

  unsigned short* WqkvcT = WT;                    // [3072][768]
  unsigned short* WoT    = WT + 2359296;          // [768][768]
  unsigned short* WiT    = WT + 2949120;          // [3072][768]
  unsigned short* Wo2T   = WT + 5308416;          // [768][3072]
  unsigned short* hb16   = qkvc16;                // FFN intermediate aliases QKVC

  cvt_dual_k<<<4096, 256, 0, stream>>>(hs, x, xb16, (int)XN);

  dim3 gGQ(FF/128, MM/128);   // 24 x 64  (QKVC, Wi)
  dim3 gGD(DD/128, MM/128);   // 6  x 64  (Wo, Wo2)
  dim3 gA(SS/64, NH, BB);     // 8 x 12 x 16 = 1536
  dim3 tDD(DD/32, DD/32);     // 24 x 24
  dim3 tDF(FF/32, DD/32);     // 96 x 24  (src [D,F])
  dim3 tFD(DD/32, FF/32);     // 24 x 96  (src [F,D])

  for (int i = 0; i < NL; ++i) {
    const size_t wD = (size_t)i*DD*DD, wF = (size_t)i*DD*FF;
    tcvt_k<<<tDD, 256, 0, stream>>>(Wq + wD, WqkvcT,            DD, DD);
    tcvt_k<<<tDD, 256, 0, stream>>>(Wk + wD, WqkvcT +  768*768, DD, DD);
    tcvt_k<<<tDD, 256, 0, stream>>>(Wv + wD, WqkvcT + 1536*768, DD, DD);
    tcvt_k<<<tDD, 256, 0, stream>>>(Wc + wD, WqkvcT + 2304*768, DD, DD);
    tcvt_k<<<tDD, 256, 0, stream>>>(Wo + wD, WoT,  DD, DD);
    tcvt_k<<<tDF, 256, 0, stream>>>(Wi + wF, WiT,  DD, FF);
    tcvt_k<<<tFD, 256, 0, stream>>>(Wo2 + wF, Wo2T, FF, DD);
    bcat_k<<<12, 256, 0, stream>>>(bq + (size_t)i*DD, bk + (size_t)i*DD,
                                   bv + (size_t)i*DD, bc + (size_t)i*DD, bqkvc);

    // fused QKVC projection: [8192,768] @ [768,3072] -> bf16 [8192,3072]
    mgemm_k<0,1><<<gGQ, 256, 0, stream>>>(xb16, WqkvcT, bqkvc, nullptr, qkvc16, MM, FF, DD);

    cnorm_k<<<nBH/4, 256, 0, stream>>>(qkvc16 + 2304, cnb);
    vtrans_k<<<gA, 256, 0, stream>>>(qkvc16 + 1536, vt16);
    attn5_k<<<gA, 256, 0, stream>>>(qkvc16, qkvc16 + 768, qkvc16 + 2304,
                                    cnb, vt16, ctx16);

    // attn_out = LN1(ctx @ Wo + bo + x)
    mgemm_k<1,0><<<gGD, 256, 0, stream>>>(ctx16, WoT, bo + (size_t)i*DD, x, attnf, MM, DD, DD);
    ln_k<<<MM, 256, 0, stream>>>(attnf, g1 + (size_t)i*DD, b1 + (size_t)i*DD, attnf, attn16);

    // h = gelu(attn @ Wi + bi) -> bf16 (overwrites dead qkvc16)
    mgemm_k<2,1><<<gGQ, 256, 0, stream>>>(attn16, WiT, bi + (size_t)i*FF, nullptr, hb16, MM, FF, DD);
    // x = LN2(h @ Wo2 + bo2 + attn); final layer writes fp32 straight to d_out
    mgemm_k<1,0><<<gGD, 256, 0, stream>>>(hb16, Wo2T, bo2 + (size_t)i*DD, attnf, x, MM, DD, FF);
    float* lnout = (i == NL-1) ? (float*)d_out : x;
    ln_k<<<MM, 256, 0, stream>>>(x, g2 + (size_t)i*DD, b2 + (size_t)i*DD, lnout, xb16);
  }
}

// Round 9
// 1429.515 us; speedup vs baseline: 1.0945x; 1.0537x over previous
//
#include <hip/hip_runtime.h>
#include <math.h>

#define DD 768
#define FF 3072
#define SS 512
#define BB 16
#define NH 12
#define DH 64
#define NL 4
#define MM (BB*SS)   // 8192

typedef __attribute__((ext_vector_type(8))) short short8;
typedef __attribute__((ext_vector_type(4))) float f32x4;

__device__ __forceinline__ unsigned short f2bf(float f) {
  unsigned u = __float_as_uint(f);
  return (unsigned short)((u + 0x7FFFu + ((u >> 16) & 1u)) >> 16);
}
__device__ __forceinline__ float bf2f(unsigned short s) {
  return __uint_as_float(((unsigned)s) << 16);
}

#define GLOAD_LDS(g, l) \
  __builtin_amdgcn_global_load_lds((const __attribute__((address_space(1))) void*)(g), \
                                   (__attribute__((address_space(3))) void*)(l), 16, 0, 0)

// ---------------- convert ----------------
__global__ __launch_bounds__(256) void cvt_dual_k(const float* __restrict__ in,
                                                  float* __restrict__ outf,
                                                  unsigned short* __restrict__ outb, int n) {
  for (int i = blockIdx.x*256 + threadIdx.x; i < n; i += gridDim.x*256) {
    float v = in[i]; outf[i] = v; outb[i] = f2bf(v);
  }
}

// fp32 [K,N] -> bf16 [N,K] tiled transpose-convert
__global__ __launch_bounds__(256) void tcvt_k(const float* __restrict__ src,
                                              unsigned short* __restrict__ dst,
                                              int K, int N) {
  __shared__ float t[32][33];
  const int n0 = blockIdx.x*32, k0 = blockIdx.y*32;
  const int tx = threadIdx.x & 31, ty = threadIdx.x >> 5;
#pragma unroll
  for (int i = 0; i < 32; i += 8)
    t[ty+i][tx] = src[(size_t)(k0+ty+i)*N + n0+tx];
  __syncthreads();
#pragma unroll
  for (int i = 0; i < 32; i += 8)
    dst[(size_t)(n0+ty+i)*K + k0+tx] = f2bf(t[tx][ty+i]);
}

// fused 5x [768,768] transpose-convert (Wq,Wk,Wv,Wc -> WqkvcT quarters; Wo -> WoT)
// one launch replaces five -> fewer launch gaps on the stream.
__global__ __launch_bounds__(256) void tcvt5_k(const float* __restrict__ Wq,
                                               const float* __restrict__ Wk,
                                               const float* __restrict__ Wv,
                                               const float* __restrict__ Wc,
                                               const float* __restrict__ Wo,
                                               unsigned long long wD,
                                               unsigned short* __restrict__ WqkvcT,
                                               unsigned short* __restrict__ WoT) {
  __shared__ float t[32][33];
  const int z = blockIdx.z;
  const float* src = ((z == 0) ? Wq : (z == 1) ? Wk : (z == 2) ? Wv :
                      (z == 3) ? Wc : Wo) + wD;
  unsigned short* dst = (z < 4) ? (WqkvcT + (size_t)z*DD*DD) : WoT;
  const int n0 = blockIdx.x*32, k0 = blockIdx.y*32;
  const int tx = threadIdx.x & 31, ty = threadIdx.x >> 5;
#pragma unroll
  for (int i = 0; i < 32; i += 8)
    t[ty+i][tx] = src[(size_t)(k0+ty+i)*DD + n0+tx];
  __syncthreads();
#pragma unroll
  for (int i = 0; i < 32; i += 8)
    dst[(size_t)(n0+ty+i)*DD + k0+tx] = f2bf(t[tx][ty+i]);
}

// concat 4x768 biases -> 3072
__global__ __launch_bounds__(256) void bcat_k(const float* __restrict__ a,
                                              const float* __restrict__ b,
                                              const float* __restrict__ c,
                                              const float* __restrict__ d,
                                              float* __restrict__ out) {
  int i = blockIdx.x*256 + threadIdx.x;   // 0..3071
  int w = i / 768;
  const float* s = (w == 0) ? a : (w == 1) ? b : (w == 2) ? c : d;
  out[i] = s[i - w*768];
}

// ---------------- 128^2 MFMA bf16 GEMM (R4 structure — best verified) ----------
// EPI: 0 bias; 1 bias+resid(fp32); 2 bias+exact gelu.  OBF: 1 -> bf16 out, 0 -> fp32.
// T1 XCD swizzle (FETCH 169->55MB, R3). T3-minimal dbuf: issue next tile's
// gload_lds BEFORE compute, drain AFTER; one barrier/K-step (83.7->73.3us, R4).
// Measured nulls/regressions, do NOT reapply: counted-vmcnt+LDS swizzle (R5),
// 256^2 8-phase (R6, 1 blk/CU), launch_bounds(256,4) (R7, null).
template<int EPI, int OBF>
__global__ __launch_bounds__(256, 3) void mgemm_k(
    const unsigned short* __restrict__ A,   // [M,K] bf16
    const unsigned short* __restrict__ Bw,  // [N,K] bf16 (pre-transposed weights)
    const float* __restrict__ bias,         // [N] fp32
    const float* __restrict__ resid,        // [M,N] fp32 (EPI==1)
    void* __restrict__ Cout, int M, int N, int K)
{
  __shared__ __align__(16) unsigned short As[2][128*32];
  __shared__ __align__(16) unsigned short Bs[2][128*32];
  const int nwg = gridDim.x * gridDim.y;
  int lin = blockIdx.y * gridDim.x + blockIdx.x;
  lin = (lin & 7) * (nwg >> 3) + (lin >> 3);
  const int bm = (lin / gridDim.x) * 128, bn = (lin % gridDim.x) * 128;
  const int tid = threadIdx.x;
  const int wave = tid >> 6, lane = tid & 63;
  const int wm = (wave >> 1)*64, wn = (wave & 1)*64;
  const int woff = wave*32*32;

  f32x4 acc[4][4] = {};

  const unsigned short* Ag = A  + (size_t)(bm + wave*32 + (lane>>2))*K + (lane&3)*8;
  const unsigned short* Bg = Bw + (size_t)(bn + wave*32 + (lane>>2))*K + (lane&3)*8;

  GLOAD_LDS(Ag,                As[0] + woff);
  GLOAD_LDS(Ag + 16*(size_t)K, As[0] + woff + 16*32);
  GLOAD_LDS(Bg,                Bs[0] + woff);
  GLOAD_LDS(Bg + 16*(size_t)K, Bs[0] + woff + 16*32);
  Ag += 32; Bg += 32;
  __syncthreads();

  const unsigned short* Ac = As[0]; unsigned short* An = As[1];
  const unsigned short* Bc = Bs[0]; unsigned short* Bn = Bs[1];
  const int nk = K >> 5;

#pragma unroll 1
  for (int t = 0; t < nk - 1; ++t) {
    GLOAD_LDS(Ag,                An + woff);
    GLOAD_LDS(Ag + 16*(size_t)K, An + woff + 16*32);
    GLOAD_LDS(Bg,                Bn + woff);
    GLOAD_LDS(Bg + 16*(size_t)K, Bn + woff + 16*32);
    Ag += 32; Bg += 32;

    short8 af[4], bfr[4];
#pragma unroll
    for (int i = 0; i < 4; ++i) {
      af[i]  = *(const short8*)&Ac[(wm + i*16 + (lane & 15))*32 + (lane >> 4)*8];
      bfr[i] = *(const short8*)&Bc[(wn + i*16 + (lane & 15))*32 + (lane >> 4)*8];
    }
    __builtin_amdgcn_s_setprio(1);
#pragma unroll
    for (int i = 0; i < 4; ++i)
#pragma unroll
      for (int j = 0; j < 4; ++j)
        acc[i][j] = __builtin_amdgcn_mfma_f32_16x16x32_bf16(af[i], bfr[j], acc[i][j], 0, 0, 0);
    __builtin_amdgcn_s_setprio(0);

    __syncthreads();
    const unsigned short* tA = Ac; Ac = An; An = (unsigned short*)tA;
    const unsigned short* tB = Bc; Bc = Bn; Bn = (unsigned short*)tB;
  }

  {
    short8 af[4], bfr[4];
#pragma unroll
    for (int i = 0; i < 4; ++i) {
      af[i]  = *(const short8*)&Ac[(wm + i*16 + (lane & 15))*32 + (lane >> 4)*8];
      bfr[i] = *(const short8*)&Bc[(wn + i*16 + (lane & 15))*32 + (lane >> 4)*8];
    }
#pragma unroll
    for (int i = 0; i < 4; ++i)
#pragma unroll
      for (int j = 0; j < 4; ++j)
        acc[i][j] = __builtin_amdgcn_mfma_f32_16x16x32_bf16(af[i], bfr[j], acc[i][j], 0, 0, 0);
  }

  const int col0 = bn + wn + (lane & 15);
  const int row0 = bm + wm + (lane >> 4)*4;
#pragma unroll
  for (int i = 0; i < 4; ++i) {
#pragma unroll
    for (int j = 0; j < 4; ++j) {
      const int n = col0 + j*16;
      const float bv = bias[n];
#pragma unroll
      for (int r = 0; r < 4; ++r) {
        const int m = row0 + i*16 + r;
        float v = acc[i][j][r] + bv;
        if (EPI == 1) v += resid[(size_t)m*N + n];
        if (EPI == 2) v = 0.5f*v*(1.0f + erff(v*0.70710678118654752f));
        if (OBF) ((unsigned short*)Cout)[(size_t)m*N + n] = f2bf(v);
        else     ((float*)Cout)[(size_t)m*N + n] = v;
      }
    }
  }
}

// ---------------- per-(b,h,s) reciprocal context-vector L2 norm ----------------
__global__ __launch_bounds__(256) void cnorm_k(const unsigned short* __restrict__ c,
                                               float* __restrict__ rn) {
  int idx = blockIdx.x*4 + (threadIdx.x >> 6);   // (b*NH + h)*SS + s
  int lane = threadIdx.x & 63;
  int s  = idx % SS;
  int bh = idx / SS;
  int h  = bh % NH;
  int b  = bh / NH;
  float v = bf2f(c[((size_t)(b*SS + s))*FF + h*DH + lane]);
  float ss = v*v;
#pragma unroll
  for (int off = 32; off; off >>= 1) ss += __shfl_xor(ss, off, 64);
  if (lane == 0) rn[idx] = rsqrtf(ss);   // store 1/||c||
}

// ---------------- V transpose: [b,s][h,d] (pitch FF) -> VT[bh][d][s] ----------------
__global__ __launch_bounds__(256) void vtrans_k(const unsigned short* __restrict__ v,
                                                unsigned short* __restrict__ VT) {
  __shared__ unsigned short t[64][72];
  const int s0 = blockIdx.x*64;
  const int h  = blockIdx.y;
  const int b  = blockIdx.z;
  const size_t base = (size_t)(b*SS)*FF + h*DH;
  const int row = threadIdx.x >> 2, seg = threadIdx.x & 3;
  const unsigned short* vg = v + base + (size_t)(s0+row)*FF + seg*16;
  *(uint4*)&t[row][seg*16]     = *(const uint4*)vg;
  *(uint4*)&t[row][seg*16 + 8] = *(const uint4*)(vg + 8);
  __syncthreads();
  unsigned short o[16];
#pragma unroll
  for (int u = 0; u < 16; ++u) o[u] = t[seg*16 + u][row];
  unsigned short* og = VT + ((size_t)(b*NH + h)*DH + row)*SS + s0 + seg*16;
  *(uint4*)og       = *(const uint4*)&o[0];
  *(uint4*)(og + 8) = *(const uint4*)&o[8];
}

// ---------------- pipelined MFMA dual-branch flash attention (R4 version) ------
// Block: (64 q-rows, h, b), 4 waves x 16 q-rows. K/C tiles in padded LDS,
// register-double-buffered staging; one barrier per iter. Fixed softmax offsets
// both branches (bounded scores; offset cancels in normalization). __expf kept:
// R7's inline-asm exp2 fold measured -7us/dispatch (asm defeats scheduling).
// XCD swizzle: 8 q-blocks of one (b,h) share an XCD's L2.
__global__ __launch_bounds__(256, 3) void attn5_k(
    const unsigned short* __restrict__ q, const unsigned short* __restrict__ k,
    const unsigned short* __restrict__ c, const float* __restrict__ rn,
    const unsigned short* __restrict__ VT, unsigned short* __restrict__ ctxO)
{
  // bijective remap: bid = x + 8y + 96z in [0,1536)
  const int bid = blockIdx.x + 8*blockIdx.y + 96*blockIdx.z;
  const int l0  = ((bid >> 3) & 7) << 6;           // q-chunk
  const int bh  = (bid & 7) + ((bid >> 6) << 3);   // (b*NH+h), same-XCD group
  const int h   = bh % NH;
  const int b   = bh / NH;
  const int tid = threadIdx.x;
  const int wave = tid >> 6, lane = tid & 63;
  const int wm = wave * 16;
  const int fr = lane & 15;     // frag row (A/B) / col (C,D)
  const int fg = lane >> 4;     // k-group (A/B) / row-quad (C,D)
  const size_t base   = (size_t)(b*SS)*FF + h*DH;
  const size_t vtbase = (size_t)bh*DH*SS;

  __shared__ __align__(16) unsigned short Ks [2][64*72];
  __shared__ __align__(16) unsigned short Crs[2][64*72];
  __shared__ __align__(16) unsigned short Ps [4][16*72];
  unsigned short* Pw = Ps[wave];

  // loop-invariant A-frags straight from global (16B contiguous)
  const unsigned short* qrow = q + base + (size_t)(l0 + wm + fr)*FF + fg*8;
  const unsigned short* crow = c + base + (size_t)(l0 + wm + fr)*FF + fg*8;
  const short8 aQ0 = *(const short8*)qrow;
  const short8 aQ1 = *(const short8*)(qrow + 32);
  const short8 aC0 = *(const short8*)crow;
  const short8 aC1 = *(const short8*)(crow + 32);

  float rnl[4];
#pragma unroll
  for (int reg = 0; reg < 4; ++reg)
    rnl[reg] = rn[(size_t)bh*SS + l0 + wm + fg*4 + reg];

  // ---- stage tile 0 (rows 0..63) ----
  const int srow = tid >> 2, sseg = tid & 3;      // 4 threads/row, 32B each
  {
    const unsigned short* kg = k + base + (size_t)srow*FF + sseg*16;
    const unsigned short* cg = c + base + (size_t)srow*FF + sseg*16;
    *(uint4*)&Ks [0][srow*72 + sseg*16]     = *(const uint4*)kg;
    *(uint4*)&Ks [0][srow*72 + sseg*16 + 8] = *(const uint4*)(kg + 8);
    *(uint4*)&Crs[0][srow*72 + sseg*16]     = *(const uint4*)cg;
    *(uint4*)&Crs[0][srow*72 + sseg*16 + 8] = *(const uint4*)(cg + 8);
  }
  __syncthreads();

  float rs2[4], rs1[4];
#pragma unroll
  for (int r = 0; r < 4; ++r) { rs2[r] = 0.f; rs1[r] = 0.f; }
  f32x4 oc1[4] = {}, oc2[4] = {};

#pragma unroll 1
  for (int it = 0; it < 8; ++it) {
    const int r0 = it*64;
    const int cur = it & 1, nxt = cur ^ 1;

    // ---- prefetch next K/C tile into registers ----
    uint4 nk0, nk1, nc0, nc1;
    if (it < 7) {
      const unsigned short* kg = k + base + (size_t)(r0 + 64 + srow)*FF + sseg*16;
      const unsigned short* cg = c + base + (size_t)(r0 + 64 + srow)*FF + sseg*16;
      nk0 = *(const uint4*)kg;  nk1 = *(const uint4*)(kg + 8);
      nc0 = *(const uint4*)cg;  nc1 = *(const uint4*)(cg + 8);
    }

    // ---- prefetch rnr + VT frags (issue early) ----
    float rnr[4];
    short8 bv0[4], bv1[4];
#pragma unroll
    for (int nt = 0; nt < 4; ++nt) {
      rnr[nt] = rn[(size_t)bh*SS + r0 + nt*16 + fr];
      const unsigned short* vtr = VT + vtbase + (size_t)(nt*16 + fr)*SS + r0 + fg*8;
      bv0[nt] = *(const short8*)vtr;
      bv1[nt] = *(const short8*)(vtr + 32);
    }

    // ---- dual scores via MFMA from staged LDS ----
    f32x4 s1a[4] = {}, s2a[4] = {};
#pragma unroll
    for (int nt = 0; nt < 4; ++nt) {
      const short8 bK0 = *(const short8*)&Ks [cur][(nt*16+fr)*72 + fg*8];
      const short8 bK1 = *(const short8*)&Ks [cur][(nt*16+fr)*72 + fg*8 + 32];
      const short8 bC0 = *(const short8*)&Crs[cur][(nt*16+fr)*72 + fg*8];
      const short8 bC1 = *(const short8*)&Crs[cur][(nt*16+fr)*72 + fg*8 + 32];
      s2a[nt] = __builtin_amdgcn_mfma_f32_16x16x32_bf16(aQ0, bK0, s2a[nt], 0,0,0);
      s2a[nt] = __builtin_amdgcn_mfma_f32_16x16x32_bf16(aQ1, bK1, s2a[nt], 0,0,0);
      s1a[nt] = __builtin_amdgcn_mfma_f32_16x16x32_bf16(aC0, bC0, s1a[nt], 0,0,0);
      s1a[nt] = __builtin_amdgcn_mfma_f32_16x16x32_bf16(aC1, bC1, s1a[nt], 0,0,0);
    }

    // ---- branch scores; D-layout: row = wm+fg*4+reg, col = nt*16+fr ----
    float sv1[4][4], sv2[4][4];   // [reg][nt]
#pragma unroll
    for (int nt = 0; nt < 4; ++nt)
#pragma unroll
      for (int reg = 0; reg < 4; ++reg) {
        const int ql = wm + fg*4 + reg;
        const int rr = nt*16 + fr;
        sv2[reg][nt] = s2a[nt][reg] * 0.125f;
        sv1[reg][nt] = 1.0f - s1a[nt][reg]*rnl[reg]*rnr[nt]
                     + ((l0+ql) == (r0+rr) ? 1.0f : 0.0f);
      }

    // ---- branch 1: fixed max, P -> frags -> PV1 ----
#pragma unroll
    for (int reg = 0; reg < 4; ++reg) {
      const int prow = (fg*4 + reg)*72;
#pragma unroll
      for (int nt = 0; nt < 4; ++nt) {
        const float x1 = __expf(sv1[reg][nt] - 3.0f);
        Pw[prow + nt*16 + fr] = f2bf(x1);
        rs1[reg] += x1;
      }
    }
    {
      const short8 p0 = *(const short8*)&Pw[fr*72 + fg*8];
      const short8 p1 = *(const short8*)&Pw[fr*72 + fg*8 + 32];
#pragma unroll
      for (int nt = 0; nt < 4; ++nt) {
        oc1[nt] = __builtin_amdgcn_mfma_f32_16x16x32_bf16(p0, bv0[nt], oc1[nt], 0,0,0);
        oc1[nt] = __builtin_amdgcn_mfma_f32_16x16x32_bf16(p1, bv1[nt], oc1[nt], 0,0,0);
      }
    }

    // ---- branch 2: fixed max (bounded |q.k|/8), same buffer (same-wave DS order) ----
#pragma unroll
    for (int reg = 0; reg < 4; ++reg) {
      const int prow = (fg*4 + reg)*72;
#pragma unroll
      for (int nt = 0; nt < 4; ++nt) {
        const float x2 = __expf(sv2[reg][nt] - 3.0f);
        Pw[prow + nt*16 + fr] = f2bf(x2);
        rs2[reg] += x2;
      }
    }
    {
      const short8 p0 = *(const short8*)&Pw[fr*72 + fg*8];
      const short8 p1 = *(const short8*)&Pw[fr*72 + fg*8 + 32];
#pragma unroll
      for (int nt = 0; nt < 4; ++nt) {
        oc2[nt] = __builtin_amdgcn_mfma_f32_16x16x32_bf16(p0, bv0[nt], oc2[nt], 0,0,0);
        oc2[nt] = __builtin_amdgcn_mfma_f32_16x16x32_bf16(p1, bv1[nt], oc2[nt], 0,0,0);
      }
    }

    // ---- commit prefetched tile to the other LDS buffer ----
    if (it < 7) {
      *(uint4*)&Ks [nxt][srow*72 + sseg*16]     = nk0;
      *(uint4*)&Ks [nxt][srow*72 + sseg*16 + 8] = nk1;
      *(uint4*)&Crs[nxt][srow*72 + sseg*16]     = nc0;
      *(uint4*)&Crs[nxt][srow*72 + sseg*16 + 8] = nc1;
    }
    __syncthreads();
  }

  // ---- final cross-lane sum reduce + blend; stage in P buffer, coalesced store ----
#pragma unroll
  for (int reg = 0; reg < 4; ++reg) {
    float t1 = rs1[reg], t2 = rs2[reg];
#pragma unroll
    for (int off = 1; off < 16; off <<= 1) {
      t1 += __shfl_xor(t1, off, 64);
      t2 += __shfl_xor(t2, off, 64);
    }
    const float i1 = 0.5f / t1;
    const float i2 = 0.5f / t2;
    const int prow = (fg*4 + reg)*72;
#pragma unroll
    for (int nt = 0; nt < 4; ++nt)
      Pw[prow + nt*16 + fr] = f2bf(oc1[nt][reg]*i1 + oc2[nt][reg]*i2);
  }
  {
    // 4 lanes per row, 2x16B each -> one full 128B line per row
    const int row = lane >> 2, seg = lane & 3;
    const int Mrow = b*SS + l0 + wm + row;
    unsigned short* og = ctxO + (size_t)Mrow*DD + h*DH + seg*16;
    *(uint4*)og       = *(const uint4*)&Pw[row*72 + seg*16];
    *(uint4*)(og + 8) = *(const uint4*)&Pw[row*72 + seg*16 + 8];
  }
}

// ---------------- row LayerNorm over D=768 (one-pass): in -> (outf, outb) ------
// Single sweep accumulates sum and sum-of-squares; var = E[x^2]-mu^2 (clamped).
// Halves LDS traffic / shuffle chains / barriers vs the 2-pass version.
__global__ __launch_bounds__(256) void ln_k(const float* __restrict__ in,
                                            const float* __restrict__ g,
                                            const float* __restrict__ b,
                                            float* __restrict__ outf,
                                            unsigned short* __restrict__ outb) {
  __shared__ float xs[DD];
  __shared__ float red[8];
  const int tid = threadIdx.x;
  const float* xr = in + (size_t)blockIdx.x * DD;
  float* xo = outf + (size_t)blockIdx.x * DD;
  unsigned short* xbr = outb + (size_t)blockIdx.x * DD;
  float s = 0.f, s2 = 0.f;
  for (int d = tid; d < DD; d += 256) {
    float v = xr[d]; xs[d] = v; s += v; s2 += v*v;
  }
#pragma unroll
  for (int off = 32; off; off >>= 1) {
    s  += __shfl_xor(s,  off, 64);
    s2 += __shfl_xor(s2, off, 64);
  }
  if ((tid & 63) == 0) { red[tid >> 6] = s; red[4 + (tid >> 6)] = s2; }
  __syncthreads();
  const float mu  = (red[0]+red[1]+red[2]+red[3]) * (1.f/DD);
  const float ex2 = (red[4]+red[5]+red[6]+red[7]) * (1.f/DD);
  const float var = fmaxf(ex2 - mu*mu, 0.f);
  const float rstd = rsqrtf(var + 1e-12f);
  for (int d = tid; d < DD; d += 256) {
    float o = (xs[d]-mu)*rstd*g[d] + b[d];
    xo[d] = o;
    xbr[d] = f2bf(o);
  }
}

// ---------------- launcher ----------------
extern "C" void kernel_launch(void* const* d_in, const int* in_sizes, int n_in,
                              void* d_out, int out_size, void* d_ws, size_t ws_size,
                              hipStream_t stream) {
  const float* hs  = (const float*)d_in[0];
  const float* Wq  = (const float*)d_in[1];  const float* bq  = (const float*)d_in[2];
  const float* Wk  = (const float*)d_in[3];  const float* bk  = (const float*)d_in[4];
  const float* Wv  = (const float*)d_in[5];  const float* bv  = (const float*)d_in[6];
  const float* Wc  = (const float*)d_in[7];  const float* bc  = (const float*)d_in[8];
  const float* Wo  = (const float*)d_in[9];  const float* bo  = (const float*)d_in[10];
  const float* g1  = (const float*)d_in[11]; const float* b1  = (const float*)d_in[12];
  const float* Wi  = (const float*)d_in[13]; const float* bi  = (const float*)d_in[14];
  const float* Wo2 = (const float*)d_in[15]; const float* bo2 = (const float*)d_in[16];
  const float* g2  = (const float*)d_in[17]; const float* b2  = (const float*)d_in[18];

  const size_t XN  = (size_t)MM * DD;       // 6,291,456
  const size_t HN  = (size_t)MM * FF;       // 25,165,824
  const int    nBH = BB*NH*SS;              // 98304
  const size_t WTN = 7667712;               // per-layer transposed weights (elems)

  char* p = (char*)d_ws;
  float*          x      = (float*)p;           p += XN*4;
  float*          attnf  = (float*)p;           p += XN*4;
  unsigned short* qkvc16 = (unsigned short*)p;  p += HN*2;   // also hb16 (aliased)
  unsigned short* xb16   = (unsigned short*)p;  p += XN*2;
  unsigned short* ctx16  = (unsigned short*)p;  p += XN*2;
  unsigned short* attn16 = (unsigned short*)p;  p += XN*2;
  unsigned short* vt16   = (unsigned short*)p;  p += XN*2;   // V^T [bh][d][s]
  unsigned short* WT     = (unsigned short*)p;  p += WTN*2;
  float*          bqkvc  = (float*)p;           p += 3072*4;
  float*          cnb    = (float*)p;           p += (size_t)nBH*4;
  const size_t need = (size_t)(p - (char*)d_ws);
  if (ws_size < need) return;

  unsigned short* WqkvcT = WT;                    // [3072][768]
  unsigned short* WoT    = WT + 2359296;          // [768][768]
  unsigned short* WiT    = WT + 2949120;          // [3072][768]
  unsigned short* Wo2T   = WT + 5308416;          // [768][3072]
  unsigned short* hb16   = qkvc16;                // FFN intermediate aliases QKVC

  cvt_dual_k<<<4096, 256, 0, stream>>>(hs, x, xb16, (int)XN);

  dim3 gGQ(FF/128, MM/128);   // 24 x 64  (QKVC, Wi)
  dim3 gGD(DD/128, MM/128);   // 6  x 64  (Wo, Wo2)
  dim3 gA(SS/64, NH, BB);     // 8 x 12 x 16 = 1536
  dim3 t5(DD/32, DD/32, 5);   // 24 x 24 x 5 (fused Wq,Wk,Wv,Wc,Wo transpose)
  dim3 tDF(FF/32, DD/32);     // 96 x 24  (src [D,F])
  dim3 tFD(DD/32, FF/32);     // 24 x 96  (src [F,D])

  for (int i = 0; i < NL; ++i) {
    const size_t wD = (size_t)i*DD*DD, wF = (size_t)i*DD*FF;
    tcvt5_k<<<t5, 256, 0, stream>>>(Wq, Wk, Wv, Wc, Wo, (unsigned long long)wD,
                                    WqkvcT, WoT);
    tcvt_k<<<tDF, 256, 0, stream>>>(Wi + wF, WiT,  DD, FF);
    tcvt_k<<<tFD, 256, 0, stream>>>(Wo2 + wF, Wo2T, FF, DD);
    bcat_k<<<12, 256, 0, stream>>>(bq + (size_t)i*DD, bk + (size_t)i*DD,
                                   bv + (size_t)i*DD, bc + (size_t)i*DD, bqkvc);

    // fused QKVC projection: [8192,768] @ [768,3072] -> bf16 [8192,3072]
    mgemm_k<0,1><<<gGQ, 256, 0, stream>>>(xb16, WqkvcT, bqkvc, nullptr, qkvc16, MM, FF, DD);

    cnorm_k<<<nBH/4, 256, 0, stream>>>(qkvc16 + 2304, cnb);
    vtrans_k<<<gA, 256, 0, stream>>>(qkvc16 + 1536, vt16);
    attn5_k<<<gA, 256, 0, stream>>>(qkvc16, qkvc16 + 768, qkvc16 + 2304,
                                    cnb, vt16, ctx16);

    // attn_out = LN1(ctx @ Wo + bo + x)
    mgemm_k<1,0><<<gGD, 256, 0, stream>>>(ctx16, WoT, bo + (size_t)i*DD, x, attnf, MM, DD, DD);
    ln_k<<<MM, 256, 0, stream>>>(attnf, g1 + (size_t)i*DD, b1 + (size_t)i*DD, attnf, attn16);

    // h = gelu(attn @ Wi + bi) -> bf16 (overwrites dead qkvc16)
    mgemm_k<2,1><<<gGQ, 256, 0, stream>>>(attn16, WiT, bi + (size_t)i*FF, nullptr, hb16, MM, FF, DD);
    // x = LN2(h @ Wo2 + bo2 + attn); final layer writes fp32 straight to d_out
    mgemm_k<1,0><<<gGD, 256, 0, stream>>>(hb16, Wo2T, bo2 + (size_t)i*DD, attnf, x, MM, DD, FF);
    float* lnout = (i == NL-1) ? (float*)d_out : x;
    ln_k<<<MM, 256, 0, stream>>>(x, g2 + (size_t)i*DD, b2 + (size_t)i*DD, lnout, xb16);
  }
}